// Round 1
// baseline (5714.896 us; speedup 1.0000x reference)
//
#include <hip/hip_runtime.h>
#include <hip/hip_bf16.h>
#include <cstdint>

#define B_   32
#define CIN  12
#define L_   1024
#define T_   64
#define C1_  64
#define C2_  128
#define K_   7
#define PAD_ 3

typedef __attribute__((ext_vector_type(8))) short short8;
typedef __attribute__((ext_vector_type(4))) float float4v;

// ---- workspace layout (bytes) ----
// s1T : bf16 [B][L][T][C1]          = 268,435,456
// w2hi: bf16 [C2][K][C1]            = 114,688
// w2lo: bf16 [C2][K][C1]            = 114,688
// accL: f32  [B][L][C2]             = 16,777,216
#define WS_S1T   0ull
#define WS_W2HI  268435456ull
#define WS_W2LO  (WS_W2HI + 114688ull)
#define WS_ACCL  (WS_W2LO + 114688ull)

// ---------------- K0: split w2 into bf16 hi/lo, layout [c2][k][c1] ----------------
__global__ __launch_bounds__(256) void k0_prep_w2(const float* __restrict__ w2,
                                                  ushort* __restrict__ w2hi,
                                                  ushort* __restrict__ w2lo) {
    int i = blockIdx.x * 256 + threadIdx.x;
    if (i >= C2_ * K_ * C1_) return;
    int c2 = i / (K_ * C1_);
    int r  = i % (K_ * C1_);
    int kk = r / C1_;
    int c1 = r % C1_;
    float w = w2[(c2 * C1_ + c1) * K_ + kk];
    __hip_bfloat16 hb = __float2bfloat16(w);
    float hf = __bfloat162float(hb);
    __hip_bfloat16 lb = __float2bfloat16(w - hf);
    ushort uh, ul;
    __builtin_memcpy(&uh, &hb, 2);
    __builtin_memcpy(&ul, &lb, 2);
    w2hi[i] = uh;
    w2lo[i] = ul;
}

// ---------------- K1: conv1 + LIF1 spike -> s1T bf16 [b][l][t][c1] ----------------
// lane = t (coalesced on t-innermost x); per-wave LDS transpose for c1-innermost store.
__global__ __launch_bounds__(256, 4) void k1_conv1(const float* __restrict__ x,
                                                   const float* __restrict__ w1,
                                                   const float* __restrict__ b1,
                                                   ushort* __restrict__ s1t) {
    __shared__ ushort Stile[4][64][72];   // [wave][t][c1 pad 72] = 36.9 KB
    int tid  = threadIdx.x;
    int w    = tid >> 6;
    int lane = tid & 63;
    int t    = lane;
    int b    = blockIdx.y;
    int lb   = blockIdx.x * 32 + w * 8;   // 8 l's per wave

    float xv[CIN * K_];

    for (int j = 0; j < 8; ++j) {
        int l = lb + j;
        // load x window [cin][dl] for this (b,l,t)
        #pragma unroll
        for (int cin = 0; cin < CIN; ++cin) {
            #pragma unroll
            for (int dl = 0; dl < K_; ++dl) {
                int gl = l + dl - PAD_;
                xv[cin * K_ + dl] = (gl >= 0 && gl < L_)
                    ? x[(((size_t)b * CIN + cin) * L_ + gl) * T_ + t] : 0.0f;
            }
        }
        // 64 output channels; w1/b1 are wave-uniform -> s_loads
        #pragma unroll 4
        for (int c1 = 0; c1 < C1_; ++c1) {
            float h = b1[c1];
            #pragma unroll
            for (int i = 0; i < CIN * K_; ++i)
                h = fmaf(w1[c1 * (CIN * K_) + i], xv[i], h);
            h *= 2.0f;                                  // GAIN
            Stile[w][t][c1] = (h >= 0.5f) ? (ushort)0x3F80 : (ushort)0;  // bf16 1.0/0.0
        }
        __syncthreads();  // ensure LDS writes visible (intra-wave ordering + uniform across waves)
        // flush: 8 x (ds_read_b128 + coalesced global_store_dwordx4), 1 KiB per instr
        size_t gbase = ((size_t)b * L_ + l) * T_ * C1_;
        #pragma unroll
        for (int m = 0; m < 8; ++m) {
            int t2  = m * 8 + (lane >> 3);
            int c1o = (lane & 7) * 8;
            uint4 v = *(const uint4*)&Stile[w][t2][c1o];
            *(uint4*)&s1t[gbase + (size_t)t2 * C1_ + c1o] = v;
        }
        __syncthreads();
    }
}

// ---------------- K2: conv2 (bf16 MFMA, hi/lo) + fused LIF2 + spike count ----------------
// Block: 1024 thr (16 waves). C-tile: 128 c2 x 512 n (n = 8 l x 64 t). K = 2 halves x 7 taps x 32 c1.
// Wave (mg,ng): mg = c2 group of 32 (2 m-tiles), ng = n group of 128 (8 n-tiles).
__global__ __launch_bounds__(1024, 4) void k2_conv2_lif(const ushort* __restrict__ s1t,
                                                        const ushort* __restrict__ w2hi,
                                                        const ushort* __restrict__ w2lo,
                                                        const float* __restrict__ b2,
                                                        float* __restrict__ accl) {
    __shared__ __align__(16) unsigned char lds_raw[71680];
    ushort* S = (ushort*)lds_raw;   // stage: [l' 14][t 64][c1r pad 40] bf16 = 71,680 B
    float*  E = (float*)lds_raw;    // epilogue: [l 8][t 64][c2r pad 33] f32 = 67,584 B

    int tid    = threadIdx.x;
    int wv     = tid >> 6;
    int lane   = tid & 63;
    int mg     = wv & 3;     // c2 group
    int ng     = wv >> 2;    // n group
    int b      = blockIdx.y;
    int lb     = blockIdx.x * 8;
    int lane15 = lane & 15;
    int kq     = lane >> 4;

    float4v acc[2][8];
    #pragma unroll
    for (int i = 0; i < 2; ++i)
        #pragma unroll
        for (int j = 0; j < 8; ++j)
            acc[i][j] = (float4v){0.0f, 0.0f, 0.0f, 0.0f};

    for (int h = 0; h < 2; ++h) {          // c1 halves of 32
        __syncthreads();
        // stage S[l'][t][0..31] = s1T[b][lb+l'-3][t][h*32 .. +32], zero outside L
        for (int it = 0; it < 4; ++it) {
            int u = it * 1024 + tid;
            if (u < 3584) {                // 14 * 64 * 4 b128-chunks
                int lp  = u >> 8;
                int rem = u & 255;
                int t   = rem >> 2;
                int g   = rem & 3;
                int gl  = lb + lp - 3;
                uint4 v = make_uint4(0u, 0u, 0u, 0u);
                if (gl >= 0 && gl < L_)
                    v = *(const uint4*)&s1t[(((size_t)b * L_ + gl) * T_ + t) * C1_ + h * 32 + g * 8];
                *(uint4*)&S[(lp * 64 + t) * 40 + g * 8] = v;
            }
        }
        __syncthreads();
        #pragma unroll
        for (int kk = 0; kk < 7; ++kk) {
            short8 ahi[2], alo[2];
            #pragma unroll
            for (int mt = 0; mt < 2; ++mt) {
                int c2 = mg * 32 + mt * 16 + lane15;          // A: m = lane&15
                size_t aoff = ((size_t)c2 * 7 + kk) * 64 + h * 32 + kq * 8;
                ahi[mt] = *(const short8*)&w2hi[aoff];
                alo[mt] = *(const short8*)&w2lo[aoff];
            }
            #pragma unroll
            for (int nt = 0; nt < 8; ++nt) {
                int l_loc = ng * 2 + (nt >> 2);
                int tt    = (nt & 3) * 16 + lane15;           // B: n = lane&15
                short8 bf = *(const short8*)&S[((l_loc + kk) * 64 + tt) * 40 + kq * 8];
                #pragma unroll
                for (int mt = 0; mt < 2; ++mt) {
                    acc[mt][nt] = __builtin_amdgcn_mfma_f32_16x16x32_bf16(ahi[mt], bf, acc[mt][nt], 0, 0, 0);
                    acc[mt][nt] = __builtin_amdgcn_mfma_f32_16x16x32_bf16(alo[mt], bf, acc[mt][nt], 0, 0, 0);
                }
            }
        }
    }

    // epilogue: 4 chunks of 32 c2 -> LDS transpose -> per-(c2,l) sequential LIF2 t-scan
    for (int cc = 0; cc < 4; ++cc) {
        __syncthreads();
        if (mg == cc) {
            #pragma unroll
            for (int mt = 0; mt < 2; ++mt)
                #pragma unroll
                for (int nt = 0; nt < 8; ++nt) {
                    int l_loc = ng * 2 + (nt >> 2);
                    int tt    = (nt & 3) * 16 + lane15;       // D: col = lane&15
                    #pragma unroll
                    for (int r = 0; r < 4; ++r) {
                        int c2r = mt * 16 + kq * 4 + r;       // D: row = quad*4 + reg
                        E[(l_loc * 64 + tt) * 33 + c2r] = acc[mt][nt][r];
                    }
                }
        }
        __syncthreads();
        if (tid < 256) {
            int c2r = tid & 31;
            int l   = tid >> 5;
            float bias = b2[cc * 32 + c2r];
            float v = 0.0f, cnt = 0.0f;
            for (int t = 0; t < 64; ++t) {
                float hh = (E[(l * 64 + t) * 33 + c2r] + bias) * 2.0f;
                v = v + (hh - v) / 0.9f;                      // match ref's division
                if (v >= 0.5f) { cnt += 1.0f; v = 0.0f; }
            }
            accl[((size_t)b * L_ + (lb + l)) * C2_ + cc * 32 + c2r] = cnt;
        }
    }
}

// ---------------- K3: mean-pool over (t,l) + fc ----------------
__global__ __launch_bounds__(128) void k3_fc(const float* __restrict__ accl,
                                             const float* __restrict__ fcw,
                                             const float* __restrict__ fcb,
                                             float* __restrict__ out) {
    __shared__ float p[C2_];
    int b = blockIdx.x, c = threadIdx.x;
    float s = 0.0f;
    for (int l = 0; l < L_; ++l)
        s += accl[((size_t)b * L_ + l) * C2_ + c];
    p[c] = s * (1.0f / 65536.0f);     // / (T * L), exact pow2
    __syncthreads();
    if (c < 4) {
        float o = fcb[c];
        #pragma unroll 8
        for (int i = 0; i < C2_; ++i)
            o = fmaf(fcw[c * C2_ + i], p[i], o);
        out[b * 4 + c] = o;
    }
}

extern "C" void kernel_launch(void* const* d_in, const int* in_sizes, int n_in,
                              void* d_out, int out_size, void* d_ws, size_t ws_size,
                              hipStream_t stream) {
    const float* x   = (const float*)d_in[0];
    const float* w1  = (const float*)d_in[1];
    const float* b1  = (const float*)d_in[2];
    const float* w2  = (const float*)d_in[3];
    const float* b2  = (const float*)d_in[4];
    const float* fcw = (const float*)d_in[5];
    const float* fcb = (const float*)d_in[6];
    float* out = (float*)d_out;

    char* ws = (char*)d_ws;
    ushort* s1t  = (ushort*)(ws + WS_S1T);
    ushort* w2h  = (ushort*)(ws + WS_W2HI);
    ushort* w2l  = (ushort*)(ws + WS_W2LO);
    float*  accl = (float*)(ws + WS_ACCL);

    k0_prep_w2<<<dim3((C2_ * K_ * C1_ + 255) / 256), dim3(256), 0, stream>>>(w2, w2h, w2l);
    k1_conv1<<<dim3(L_ / 32, B_), dim3(256), 0, stream>>>(x, w1, b1, s1t);
    k2_conv2_lif<<<dim3(L_ / 8, B_), dim3(1024), 0, stream>>>(s1t, w2h, w2l, b2, accl);
    k3_fc<<<dim3(B_), dim3(128), 0, stream>>>(accl, fcw, fcb, out);
}

// Round 2
// 1937.972 us; speedup vs baseline: 2.9489x; 2.9489x over previous
//
#include <hip/hip_runtime.h>
#include <hip/hip_bf16.h>
#include <cstdint>

#define B_   32
#define CIN  12
#define L_   1024
#define T_   64
#define C1_  64
#define C2_  128
#define K_   7
#define PAD_ 3

typedef __attribute__((ext_vector_type(8))) short short8;
typedef __attribute__((ext_vector_type(4))) float float4v;

// ---- workspace layout (bytes) ----
// s1T : bf16 [B][L][T][C1]          = 268,435,456
// w2hi: bf16 [C2][K][C1]            = 114,688
// w2lo: bf16 [C2][K][C1]            = 114,688
// accL: f32  [B][L][C2]             = 16,777,216
#define WS_S1T   0ull
#define WS_W2HI  268435456ull
#define WS_W2LO  (WS_W2HI + 114688ull)
#define WS_ACCL  (WS_W2LO + 114688ull)

// ---------------- K0: split w2 into bf16 hi/lo, layout [c2][k][c1] ----------------
__global__ __launch_bounds__(256) void k0_prep_w2(const float* __restrict__ w2,
                                                  ushort* __restrict__ w2hi,
                                                  ushort* __restrict__ w2lo) {
    int i = blockIdx.x * 256 + threadIdx.x;
    if (i >= C2_ * K_ * C1_) return;
    int c2 = i / (K_ * C1_);
    int r  = i % (K_ * C1_);
    int kk = r / C1_;
    int c1 = r % C1_;
    float w = w2[(c2 * C1_ + c1) * K_ + kk];
    __hip_bfloat16 hb = __float2bfloat16(w);
    float hf = __bfloat162float(hb);
    __hip_bfloat16 lb = __float2bfloat16(w - hf);
    ushort uh, ul;
    __builtin_memcpy(&uh, &hb, 2);
    __builtin_memcpy(&ul, &lb, 2);
    w2hi[i] = uh;
    w2lo[i] = ul;
}

// ---------------- K1: conv1 + LIF1 spike -> s1T bf16 [b][l][t][c1] ----------------
// lane = t (coalesced on t-innermost x); per-wave LDS transpose for c1-innermost store.
// launch_bounds(256,2): xv[84] MUST stay in VGPRs (min-waves 4 forced a 64-VGPR
// allocation and spilled xv to scratch -> 13 GB HBM traffic, 4850 us).
__global__ __launch_bounds__(256, 2) void k1_conv1(const float* __restrict__ x,
                                                   const float* __restrict__ w1,
                                                   const float* __restrict__ b1,
                                                   ushort* __restrict__ s1t) {
    __shared__ ushort Stile[4][64][72];   // [wave][t][c1 pad 72] = 36.9 KB
    int tid  = threadIdx.x;
    int w    = tid >> 6;
    int lane = tid & 63;
    int t    = lane;
    int b    = blockIdx.y;
    int lb   = blockIdx.x * 32 + w * 8;   // 8 l's per wave

    float xv[CIN * K_];

    for (int j = 0; j < 8; ++j) {
        int l = lb + j;
        // load x window [cin][dl] for this (b,l,t)
        #pragma unroll
        for (int cin = 0; cin < CIN; ++cin) {
            #pragma unroll
            for (int dl = 0; dl < K_; ++dl) {
                int gl = l + dl - PAD_;
                xv[cin * K_ + dl] = (gl >= 0 && gl < L_)
                    ? x[(((size_t)b * CIN + cin) * L_ + gl) * T_ + t] : 0.0f;
            }
        }
        // 64 output channels; w1/b1 are wave-uniform -> s_loads
        #pragma unroll 4
        for (int c1 = 0; c1 < C1_; ++c1) {
            float h = b1[c1];
            #pragma unroll
            for (int i = 0; i < CIN * K_; ++i)
                h = fmaf(w1[c1 * (CIN * K_) + i], xv[i], h);
            h *= 2.0f;                                  // GAIN
            Stile[w][t][c1] = (h >= 0.5f) ? (ushort)0x3F80 : (ushort)0;  // bf16 1.0/0.0
        }
        __syncthreads();  // ensure LDS writes visible (intra-wave ordering + uniform across waves)
        // flush: 8 x (ds_read_b128 + coalesced global_store_dwordx4), 1 KiB per instr
        size_t gbase = ((size_t)b * L_ + l) * T_ * C1_;
        #pragma unroll
        for (int m = 0; m < 8; ++m) {
            int t2  = m * 8 + (lane >> 3);
            int c1o = (lane & 7) * 8;
            uint4 v = *(const uint4*)&Stile[w][t2][c1o];
            *(uint4*)&s1t[gbase + (size_t)t2 * C1_ + c1o] = v;
        }
        __syncthreads();
    }
}

// ---------------- K2: conv2 (bf16 MFMA, hi/lo) + fused LIF2 + spike count ----------------
// Block: 1024 thr (16 waves). C-tile: 128 c2 x 512 n (n = 8 l x 64 t). K = 2 halves x 7 taps x 32 c1.
// Wave (mg,ng): mg = c2 group of 32 (2 m-tiles), ng = n group of 128 (8 n-tiles).
__global__ __launch_bounds__(1024, 4) void k2_conv2_lif(const ushort* __restrict__ s1t,
                                                        const ushort* __restrict__ w2hi,
                                                        const ushort* __restrict__ w2lo,
                                                        const float* __restrict__ b2,
                                                        float* __restrict__ accl) {
    __shared__ __align__(16) unsigned char lds_raw[71680];
    ushort* S = (ushort*)lds_raw;   // stage: [l' 14][t 64][c1r pad 40] bf16 = 71,680 B
    float*  E = (float*)lds_raw;    // epilogue: [l 8][t 64][c2r pad 33] f32 = 67,584 B

    int tid    = threadIdx.x;
    int wv     = tid >> 6;
    int lane   = tid & 63;
    int mg     = wv & 3;     // c2 group
    int ng     = wv >> 2;    // n group
    int b      = blockIdx.y;
    int lb     = blockIdx.x * 8;
    int lane15 = lane & 15;
    int kq     = lane >> 4;

    float4v acc[2][8];
    #pragma unroll
    for (int i = 0; i < 2; ++i)
        #pragma unroll
        for (int j = 0; j < 8; ++j)
            acc[i][j] = (float4v){0.0f, 0.0f, 0.0f, 0.0f};

    for (int h = 0; h < 2; ++h) {          // c1 halves of 32
        __syncthreads();
        // stage S[l'][t][0..31] = s1T[b][lb+l'-3][t][h*32 .. +32], zero outside L
        for (int it = 0; it < 4; ++it) {
            int u = it * 1024 + tid;
            if (u < 3584) {                // 14 * 64 * 4 b128-chunks
                int lp  = u >> 8;
                int rem = u & 255;
                int t   = rem >> 2;
                int g   = rem & 3;
                int gl  = lb + lp - 3;
                uint4 v = make_uint4(0u, 0u, 0u, 0u);
                if (gl >= 0 && gl < L_)
                    v = *(const uint4*)&s1t[(((size_t)b * L_ + gl) * T_ + t) * C1_ + h * 32 + g * 8];
                *(uint4*)&S[(lp * 64 + t) * 40 + g * 8] = v;
            }
        }
        __syncthreads();
        #pragma unroll
        for (int kk = 0; kk < 7; ++kk) {
            short8 ahi[2], alo[2];
            #pragma unroll
            for (int mt = 0; mt < 2; ++mt) {
                int c2 = mg * 32 + mt * 16 + lane15;          // A: m = lane&15
                size_t aoff = ((size_t)c2 * 7 + kk) * 64 + h * 32 + kq * 8;
                ahi[mt] = *(const short8*)&w2hi[aoff];
                alo[mt] = *(const short8*)&w2lo[aoff];
            }
            #pragma unroll
            for (int nt = 0; nt < 8; ++nt) {
                int l_loc = ng * 2 + (nt >> 2);
                int tt    = (nt & 3) * 16 + lane15;           // B: n = lane&15
                short8 bf = *(const short8*)&S[((l_loc + kk) * 64 + tt) * 40 + kq * 8];
                #pragma unroll
                for (int mt = 0; mt < 2; ++mt) {
                    acc[mt][nt] = __builtin_amdgcn_mfma_f32_16x16x32_bf16(ahi[mt], bf, acc[mt][nt], 0, 0, 0);
                    acc[mt][nt] = __builtin_amdgcn_mfma_f32_16x16x32_bf16(alo[mt], bf, acc[mt][nt], 0, 0, 0);
                }
            }
        }
    }

    // epilogue: 4 chunks of 32 c2 -> LDS transpose -> per-(c2,l) sequential LIF2 t-scan
    for (int cc = 0; cc < 4; ++cc) {
        __syncthreads();
        if (mg == cc) {
            #pragma unroll
            for (int mt = 0; mt < 2; ++mt)
                #pragma unroll
                for (int nt = 0; nt < 8; ++nt) {
                    int l_loc = ng * 2 + (nt >> 2);
                    int tt    = (nt & 3) * 16 + lane15;       // D: col = lane&15
                    #pragma unroll
                    for (int r = 0; r < 4; ++r) {
                        int c2r = mt * 16 + kq * 4 + r;       // D: row = quad*4 + reg
                        E[(l_loc * 64 + tt) * 33 + c2r] = acc[mt][nt][r];
                    }
                }
        }
        __syncthreads();
        if (tid < 256) {
            int c2r = tid & 31;
            int l   = tid >> 5;
            float bias = b2[cc * 32 + c2r];
            float v = 0.0f, cnt = 0.0f;
            for (int t = 0; t < 64; ++t) {
                float hh = (E[(l * 64 + t) * 33 + c2r] + bias) * 2.0f;
                v = v + (hh - v) / 0.9f;                      // match ref's division
                if (v >= 0.5f) { cnt += 1.0f; v = 0.0f; }
            }
            accl[((size_t)b * L_ + (lb + l)) * C2_ + cc * 32 + c2r] = cnt;
        }
    }
}

// ---------------- K3: mean-pool over (t,l) + fc ----------------
__global__ __launch_bounds__(128) void k3_fc(const float* __restrict__ accl,
                                             const float* __restrict__ fcw,
                                             const float* __restrict__ fcb,
                                             float* __restrict__ out) {
    __shared__ float p[C2_];
    int b = blockIdx.x, c = threadIdx.x;
    float s = 0.0f;
    for (int l = 0; l < L_; ++l)
        s += accl[((size_t)b * L_ + l) * C2_ + c];
    p[c] = s * (1.0f / 65536.0f);     // / (T * L), exact pow2
    __syncthreads();
    if (c < 4) {
        float o = fcb[c];
        #pragma unroll 8
        for (int i = 0; i < C2_; ++i)
            o = fmaf(fcw[c * C2_ + i], p[i], o);
        out[b * 4 + c] = o;
    }
}

extern "C" void kernel_launch(void* const* d_in, const int* in_sizes, int n_in,
                              void* d_out, int out_size, void* d_ws, size_t ws_size,
                              hipStream_t stream) {
    const float* x   = (const float*)d_in[0];
    const float* w1  = (const float*)d_in[1];
    const float* b1  = (const float*)d_in[2];
    const float* w2  = (const float*)d_in[3];
    const float* b2  = (const float*)d_in[4];
    const float* fcw = (const float*)d_in[5];
    const float* fcb = (const float*)d_in[6];
    float* out = (float*)d_out;

    char* ws = (char*)d_ws;
    ushort* s1t  = (ushort*)(ws + WS_S1T);
    ushort* w2h  = (ushort*)(ws + WS_W2HI);
    ushort* w2l  = (ushort*)(ws + WS_W2LO);
    float*  accl = (float*)(ws + WS_ACCL);

    k0_prep_w2<<<dim3((C2_ * K_ * C1_ + 255) / 256), dim3(256), 0, stream>>>(w2, w2h, w2l);
    k1_conv1<<<dim3(L_ / 32, B_), dim3(256), 0, stream>>>(x, w1, b1, s1t);
    k2_conv2_lif<<<dim3(L_ / 8, B_), dim3(1024), 0, stream>>>(s1t, w2h, w2l, b2, accl);
    k3_fc<<<dim3(B_), dim3(128), 0, stream>>>(accl, fcw, fcb, out);
}